// Round 8
// baseline (30247.922 us; speedup 1.0000x reference)
//
#include <hip/hip_runtime.h>
#include <hip/hip_bf16.h>

#ifndef NEG_SLOPE
#define NEG_SLOPE 0.2f
#endif

static inline int cdiv(long long a, long long b) { return (int)((a + b - 1) / b); }

__device__ __forceinline__ float lrelu(float v) { return v > 0.f ? v : NEG_SLOPE * v; }

// ---- build extended weights for all 3 layers in one launch (block b = layer b)
// wext rows [0,FOUT) = W; row FOUT+h = (W^T al) fold; row FOUT+H+h = (W^T ar) fold.
__global__ void k_build_wext(const float* __restrict__ W1, const float* __restrict__ al1,
                             const float* __restrict__ ar1, const float* __restrict__ W2,
                             const float* __restrict__ al2, const float* __restrict__ ar2,
                             const float* __restrict__ W3, const float* __restrict__ al3,
                             const float* __restrict__ ar3, float* __restrict__ wx1,
                             float* __restrict__ wx2, float* __restrict__ wx3) {
    int b = blockIdx.x;
    const float *W, *al, *ar;
    float* wx;
    int FIN, FOUT, H, D;
    if (b == 0) { W = W1; al = al1; ar = ar1; wx = wx1; FIN = 25; FOUT = 40; H = 4; D = 10; }
    else if (b == 1) { W = W2; al = al2; ar = ar2; wx = wx2; FIN = 40; FOUT = 100; H = 4; D = 25; }
    else { W = W3; al = al3; ar = ar3; wx = wx3; FIN = 100; FOUT = 50; H = 1; D = 50; }
    for (int i = threadIdx.x; i < FOUT * FIN; i += blockDim.x) wx[i] = W[i];
    for (int i = threadIdx.x; i < 2 * H * FIN; i += blockDim.x) {
        int row = i / FIN, k = i % FIN;
        int h = row % H, isR = row / H;
        const float* a = isR ? ar : al;
        float s = 0.f;
        for (int d = 0; d < D; ++d) s += W[(h * D + d) * FIN + k] * a[h * D + d];
        wx[(FOUT + isR * H + h) * FIN + k] = s;
    }
}

// ---- fused linear + scores: one pass produces h, el, er from wext
template <int FIN, int FOUT, int H>
__global__ void k_linear(const float* __restrict__ x, const float* __restrict__ wx,
                         float* __restrict__ h, float* __restrict__ el, float* __restrict__ er,
                         int n_nodes) {
    constexpr int FOUTE = FOUT + 2 * H;
    __shared__ float Ws[FIN * FOUTE];
    for (int i = threadIdx.x; i < FIN * FOUTE; i += blockDim.x) {
        int f = i / FIN, k = i % FIN;
        Ws[k * FOUTE + f] = wx[i];
    }
    __syncthreads();
    int idx = blockIdx.x * blockDim.x + threadIdx.x;
    if (idx >= n_nodes * FOUTE) return;
    int n = idx / FOUTE, f = idx % FOUTE;
    const float* __restrict__ xr = x + (long long)n * FIN;
    float acc = 0.f;
#pragma unroll
    for (int k = 0; k < FIN; ++k) acc += xr[k] * Ws[k * FOUTE + f];
    if (f < FOUT) h[(long long)n * FOUT + f] = acc;
    else if (f < FOUT + H) el[n * H + (f - FOUT)] = acc;
    else er[n * H + (f - FOUT - H)] = acc;
}

// ================= CSR build ==========
__global__ void k_deg(const int* __restrict__ dst, int* __restrict__ deg, int n_edges) {
    int e = blockIdx.x * blockDim.x + threadIdx.x;
    if (e >= n_edges) return;
    atomicAdd(&deg[dst[e]], 1);
}

__global__ void k_scan_block(const int* __restrict__ deg, int* __restrict__ incl,
                             int* __restrict__ blocksum, int n) {
    __shared__ int tmp[256];
    int t = threadIdx.x;
    int i = blockIdx.x * 256 + t;
    int v = (i < n) ? deg[i] : 0;
    tmp[t] = v;
    __syncthreads();
    for (int off = 1; off < 256; off <<= 1) {
        int add = (t >= off) ? tmp[t - off] : 0;
        __syncthreads();
        tmp[t] += add;
        __syncthreads();
    }
    if (i < n) incl[i] = tmp[t];
    if (t == 255) blocksum[blockIdx.x] = tmp[t];
}

__global__ void k_scan_top(const int* __restrict__ blocksum, int* __restrict__ blockoff, int nb) {
    __shared__ int tmp[256];
    int t = threadIdx.x;
    int base = 0;
    for (int c = 0; c < nb; c += 256) {
        int i = c + t;
        int v = (i < nb) ? blocksum[i] : 0;
        tmp[t] = v;
        __syncthreads();
        for (int off = 1; off < 256; off <<= 1) {
            int add = (t >= off) ? tmp[t - off] : 0;
            __syncthreads();
            tmp[t] += add;
            __syncthreads();
        }
        if (i < nb) blockoff[i] = base + tmp[t] - v;
        base += tmp[255];
        __syncthreads();
    }
}

__global__ void k_scan_finalize(const int* __restrict__ incl, const int* __restrict__ deg,
                                const int* __restrict__ blockoff, int* __restrict__ rowptr,
                                int n, int n_edges) {
    int i = blockIdx.x * blockDim.x + threadIdx.x;
    if (i < n) rowptr[i] = incl[i] - deg[i] + blockoff[i / 256];
    if (i == 0) rowptr[n] = n_edges;
}

__global__ void k_fill(const int* __restrict__ src, const int* __restrict__ dst,
                       const int* __restrict__ rowptr, int* __restrict__ cursor,
                       int* __restrict__ csr_src, int n_edges) {
    int e = blockIdx.x * blockDim.x + threadIdx.x;
    if (e >= n_edges) return;
    int d = dst[e];
    int pos = atomicAdd(&cursor[d], 1);
    csr_src[rowptr[d] + pos] = src[e];
}

// wave-parallel rank sort: one wave per node (deterministic sorted order).
__global__ void k_sort_wave(const int* __restrict__ rowptr, int* __restrict__ csr_src,
                            int n_nodes) {
    int wid = (blockIdx.x * blockDim.x + threadIdx.x) >> 6;
    int lane = threadIdx.x & 63;
    if (wid >= n_nodes) return;
    int s0 = rowptr[wid], e0 = rowptr[wid + 1];
    int d = e0 - s0;
    if (d <= 1) return;
    if (d <= 64) {
        int v = (lane < d) ? csr_src[s0 + lane] : 0x7FFFFFFF;
        int rank = 0;
        for (int k = 0; k < d; ++k) {
            int vk = __shfl(v, k);
            rank += (vk < v || (vk == v && k < lane)) ? 1 : 0;
        }
        if (lane < d) csr_src[s0 + rank] = v;
    } else if (lane == 0) {
        for (int a = s0 + 1; a < e0; ++a) {
            int key = csr_src[a];
            int b = a - 1;
            while (b >= s0 && csr_src[b] > key) { csr_src[b + 1] = csr_src[b]; --b; }
            csr_src[b + 1] = key;
        }
    }
}

// ================= fused per-node attention (persistent waves, float2 rows) ===========
// alpha = exp(v)/sum(exp(v)) (== exp(v-m)/sum form exactly; |v| ~<25 here, no overflow).
// Persistent grid-stride: nwaves total waves, each walks nodes wid, wid+nwaves, ...
//   p-role: lane -> edge slot lane/H, head lane%H  (EB*H <= 64 slots).
//   f-role: lane<P owns feature pair {2*lane, 2*lane+1} -> ONE dwordx2 per edge.
// Flat statically-indexed burst buffer hv[EB*2] (proven no-spill shape), next-batch
// prefetch of csr_src + el; denominator via one shfl_xor butterfly per batch.
template <int FOUT, int H, int D, int EB>
__global__ void k_node_gather(const int* __restrict__ rowptr, const int* __restrict__ csr_src,
                              const float* __restrict__ el, const float* __restrict__ er,
                              const float* __restrict__ h, const float* __restrict__ bias,
                              float* __restrict__ xout, int n_nodes, int nwaves) {
    constexpr int P = FOUT / 2;  // feature pairs (FOUT even)
    int wave0 = (blockIdx.x * blockDim.x + threadIdx.x) >> 6;
    int lane = threadIdx.x & 63;

    const int eidx = lane / H;
    const int hh_c = lane % H;
    const bool isF = lane < P;
    // per-component head mapping for the float2 chunk (static, node-independent)
    const int hhA = isF ? (2 * lane) / D : 0;
    const int hhB = isF ? (2 * lane + 1) / D : 0;

    for (int wid = wave0; wid < n_nodes; wid += nwaves) {
        int start = rowptr[wid], end = rowptr[wid + 1];
        const float er_c = er[wid * H + hh_c];

        float acc0 = 0.f, acc1 = 0.f, den_acc = 0.f;

        if (start < end) {
            int j0 = start;
            int nb = end - j0;
            if (nb > EB) nb = EB;
            int s_c = csr_src[j0 + (eidx < nb ? eidx : 0)];
            float e_c = el[s_c * H + hh_c];

            while (true) {
                int j1 = j0 + nb;
                int nbn = end - j1;
                if (nbn > EB) nbn = EB;
                int s_n = 0;
                float e_n = 0.f;
                if (nbn > 0) {  // prefetch next batch ids + el (hides latency under FMAs)
                    s_n = csr_src[j1 + (eidx < nbn ? eidx : 0)];
                    e_n = el[s_n * H + hh_c];
                }
                // probability (one per p-slot) + butterfly denominator
                float p_c = expf(lrelu(e_c + er_c));
                float pd = (eidx < nb) ? p_c : 0.f;
#pragma unroll
                for (int st = H; st < 64; st <<= 1) pd += __shfl_xor(pd, st);
                den_acc += pd;

                // burst-load edge rows: one float2 per lane per edge (static indexing)
                float hv[EB * 2];
#pragma unroll
                for (int e = 0; e < EB; ++e) {
                    if (e < nb) {  // nb wave-uniform
                        int s = __shfl(s_c, e * H);
                        if (isF) {
                            float2 t = ((const float2*)(h + (long long)s * FOUT))[lane];
                            hv[e * 2] = t.x;
                            hv[e * 2 + 1] = t.y;
                        }
                    }
                }
                // consume
#pragma unroll
                for (int e = 0; e < EB; ++e) {
                    if (e < nb) {
                        float pA = __shfl(p_c, e * H + hhA);
                        float pB = __shfl(p_c, e * H + hhB);
                        if (isF) {
                            acc0 += pA * hv[e * 2];
                            acc1 += pB * hv[e * 2 + 1];
                        }
                    }
                }
                if (nbn <= 0) break;
                j0 = j1;
                nb = nbn;
                s_c = s_n;
                e_c = e_n;
            }
        }

        // epilogue: den shfls outside the divergent f-guard
        float dA = __shfl(den_acc, hhA);
        float dB = __shfl(den_acc, hhB);
        if (isF) {
            float2 bv = ((const float2*)bias)[lane];
            float v0, v1;
            if (end > start) {
                v0 = acc0 / dA + bv.x;
                v1 = acc1 / dB + bv.y;
            } else {
                v0 = bv.x;
                v1 = bv.y;
            }
            float2 o;
            o.x = v0 > 0.f ? v0 : 0.f;
            o.y = v1 > 0.f ? v1 : 0.f;
            ((float2*)(xout + (long long)wid * FOUT))[lane] = o;
        }
    }
}

// ---- final FC: out = x @ W.T + b (transposed LDS staging)
template <int FIN, int FOUT>
__global__ void k_fc(const float* __restrict__ x, const float* __restrict__ W,
                     const float* __restrict__ b, float* __restrict__ out, int n_nodes) {
    __shared__ float Ws[FIN * FOUT];
    for (int i = threadIdx.x; i < FIN * FOUT; i += blockDim.x) {
        int f = i / FIN, k = i % FIN;
        Ws[k * FOUT + f] = W[i];
    }
    __syncthreads();
    int idx = blockIdx.x * blockDim.x + threadIdx.x;
    if (idx >= n_nodes * FOUT) return;
    int n = idx / FOUT, f = idx % FOUT;
    const float* __restrict__ xr = x + (long long)n * FIN;
    float acc = b[f];
#pragma unroll
    for (int k = 0; k < FIN; ++k) acc += xr[k] * Ws[k * FOUT + f];
    out[idx] = acc;
}

template <int FIN, int FOUT, int H, int D, int EB>
static void gat_layer(const float* x, const float* wext, const float* bias, const int* rowptr,
                      const int* csr_src, int n_nodes, float* bufH, float* el, float* er,
                      float* xnext, hipStream_t stream) {
    constexpr int FOUTE = FOUT + 2 * H;
    k_linear<FIN, FOUT, H><<<cdiv((long long)n_nodes * FOUTE, 256), 256, 0, stream>>>(
        x, wext, bufH, el, er, n_nodes);
    // persistent: 2048 blocks (8/CU) x 4 waves = 8192 resident waves
    const int gblocks = 2048;
    const int nwaves = gblocks * (256 / 64);
    k_node_gather<FOUT, H, D, EB><<<gblocks, 256, 0, stream>>>(rowptr, csr_src, el, er, bufH,
                                                               bias, xnext, n_nodes, nwaves);
}

extern "C" void kernel_launch(void* const* d_in, const int* in_sizes, int n_in,
                              void* d_out, int out_size, void* d_ws, size_t ws_size,
                              hipStream_t stream) {
    const float* features = (const float*)d_in[0];
    const int* src = (const int*)d_in[1];
    const int* dst = (const int*)d_in[2];
    const float* W1 = (const float*)d_in[3];
    const float* al1 = (const float*)d_in[4];
    const float* ar1 = (const float*)d_in[5];
    const float* b1 = (const float*)d_in[6];
    const float* W2 = (const float*)d_in[7];
    const float* al2 = (const float*)d_in[8];
    const float* ar2 = (const float*)d_in[9];
    const float* b2 = (const float*)d_in[10];
    const float* W3 = (const float*)d_in[11];
    const float* al3 = (const float*)d_in[12];
    const float* ar3 = (const float*)d_in[13];
    const float* b3 = (const float*)d_in[14];
    const float* fc_w = (const float*)d_in[15];
    const float* fc_b = (const float*)d_in[16];

    const int n_nodes = in_sizes[0] / 25;  // 50000
    const int n_edges = in_sizes[1];       // 1000000
    const int nblocks_nodes = cdiv(n_nodes, 256);

    char* ws = (char*)d_ws;
    size_t off = 0;
    auto alloc = [&](size_t bytes) {
        char* p = ws + off;
        off += (bytes + 255) & ~(size_t)255;
        return p;
    };
    float* bufA = (float*)alloc((size_t)n_nodes * 100 * sizeof(float));
    float* bufH = (float*)alloc((size_t)n_nodes * 100 * sizeof(float));
    float* el = (float*)alloc((size_t)n_nodes * 4 * sizeof(float));
    float* er = (float*)alloc((size_t)n_nodes * 4 * sizeof(float));
    int* degcur = (int*)alloc((size_t)2 * n_nodes * sizeof(int));  // deg | cursor
    int* deg = degcur;
    int* cursor = degcur + n_nodes;
    int* incl = (int*)alloc((size_t)n_nodes * sizeof(int));
    int* blocksum = (int*)alloc((size_t)nblocks_nodes * sizeof(int));
    int* blockoff = (int*)alloc((size_t)nblocks_nodes * sizeof(int));
    int* rowptr = (int*)alloc((size_t)(n_nodes + 1) * sizeof(int));
    int* csr_src = (int*)alloc((size_t)n_edges * sizeof(int));
    float* wx1 = (float*)alloc((size_t)48 * 25 * sizeof(float));
    float* wx2 = (float*)alloc((size_t)108 * 40 * sizeof(float));
    float* wx3 = (float*)alloc((size_t)52 * 100 * sizeof(float));
    (void)ws_size;

    // extended weights (all layers, one launch)
    k_build_wext<<<3, 256, 0, stream>>>(W1, al1, ar1, W2, al2, ar2, W3, al3, ar3, wx1, wx2, wx3);

    // ---- build CSR by dst (shared across all 3 layers)
    hipMemsetAsync(degcur, 0, (size_t)2 * n_nodes * sizeof(int), stream);
    k_deg<<<cdiv(n_edges, 256), 256, 0, stream>>>(dst, deg, n_edges);
    k_scan_block<<<nblocks_nodes, 256, 0, stream>>>(deg, incl, blocksum, n_nodes);
    k_scan_top<<<1, 256, 0, stream>>>(blocksum, blockoff, nblocks_nodes);
    k_scan_finalize<<<cdiv(n_nodes + 1, 256), 256, 0, stream>>>(incl, deg, blockoff, rowptr,
                                                                n_nodes, n_edges);
    k_fill<<<cdiv(n_edges, 256), 256, 0, stream>>>(src, dst, rowptr, cursor, csr_src, n_edges);
    k_sort_wave<<<cdiv((long long)n_nodes * 64, 256), 256, 0, stream>>>(rowptr, csr_src,
                                                                        n_nodes);

    // ---- 3 GAT layers
    gat_layer<25, 40, 4, 10, 16>(features, wx1, b1, rowptr, csr_src, n_nodes, bufH, el, er,
                                 bufA, stream);
    gat_layer<40, 100, 4, 25, 16>(bufA, wx2, b2, rowptr, csr_src, n_nodes, bufH, el, er,
                                  bufA, stream);
    gat_layer<100, 50, 1, 50, 32>(bufA, wx3, b3, rowptr, csr_src, n_nodes, bufH, el, er,
                                  bufA, stream);

    // ---- final FC: 50 -> 93
    k_fc<50, 93><<<cdiv((long long)n_nodes * 93, 256), 256, 0, stream>>>(
        bufA, fc_w, fc_b, (float*)d_out, n_nodes);
}

// Round 9
// 524.797 us; speedup vs baseline: 57.6374x; 57.6374x over previous
//
#include <hip/hip_runtime.h>
#include <hip/hip_bf16.h>

#ifndef NEG_SLOPE
#define NEG_SLOPE 0.2f
#endif

static inline int cdiv(long long a, long long b) { return (int)((a + b - 1) / b); }

__device__ __forceinline__ float lrelu(float v) { return v > 0.f ? v : NEG_SLOPE * v; }

// ---- build extended weights for all 3 layers in one launch (block b = layer b)
// wext rows [0,FOUT) = W; row FOUT+h = (W^T al) fold; row FOUT+H+h = (W^T ar) fold.
__global__ void k_build_wext(const float* __restrict__ W1, const float* __restrict__ al1,
                             const float* __restrict__ ar1, const float* __restrict__ W2,
                             const float* __restrict__ al2, const float* __restrict__ ar2,
                             const float* __restrict__ W3, const float* __restrict__ al3,
                             const float* __restrict__ ar3, float* __restrict__ wx1,
                             float* __restrict__ wx2, float* __restrict__ wx3) {
    int b = blockIdx.x;
    const float *W, *al, *ar;
    float* wx;
    int FIN, FOUT, H, D;
    if (b == 0) { W = W1; al = al1; ar = ar1; wx = wx1; FIN = 25; FOUT = 40; H = 4; D = 10; }
    else if (b == 1) { W = W2; al = al2; ar = ar2; wx = wx2; FIN = 40; FOUT = 100; H = 4; D = 25; }
    else { W = W3; al = al3; ar = ar3; wx = wx3; FIN = 100; FOUT = 50; H = 1; D = 50; }
    for (int i = threadIdx.x; i < FOUT * FIN; i += blockDim.x) wx[i] = W[i];
    for (int i = threadIdx.x; i < 2 * H * FIN; i += blockDim.x) {
        int row = i / FIN, k = i % FIN;
        int h = row % H, isR = row / H;
        const float* a = isR ? ar : al;
        float s = 0.f;
        for (int d = 0; d < D; ++d) s += W[(h * D + d) * FIN + k] * a[h * D + d];
        wx[(FOUT + isR * H + h) * FIN + k] = s;
    }
}

// ---- fused linear + scores: one pass produces h, el, er from wext
template <int FIN, int FOUT, int H>
__global__ void k_linear(const float* __restrict__ x, const float* __restrict__ wx,
                         float* __restrict__ h, float* __restrict__ el, float* __restrict__ er,
                         int n_nodes) {
    constexpr int FOUTE = FOUT + 2 * H;
    __shared__ float Ws[FIN * FOUTE];
    for (int i = threadIdx.x; i < FIN * FOUTE; i += blockDim.x) {
        int f = i / FIN, k = i % FIN;
        Ws[k * FOUTE + f] = wx[i];
    }
    __syncthreads();
    int idx = blockIdx.x * blockDim.x + threadIdx.x;
    if (idx >= n_nodes * FOUTE) return;
    int n = idx / FOUTE, f = idx % FOUTE;
    const float* __restrict__ xr = x + (long long)n * FIN;
    float acc = 0.f;
#pragma unroll
    for (int k = 0; k < FIN; ++k) acc += xr[k] * Ws[k * FOUTE + f];
    if (f < FOUT) h[(long long)n * FOUT + f] = acc;
    else if (f < FOUT + H) el[n * H + (f - FOUT)] = acc;
    else er[n * H + (f - FOUT - H)] = acc;
}

// ================= CSR build ==========
__global__ void k_deg(const int* __restrict__ dst, int* __restrict__ deg, int n_edges) {
    int e = blockIdx.x * blockDim.x + threadIdx.x;
    if (e >= n_edges) return;
    atomicAdd(&deg[dst[e]], 1);
}

__global__ void k_scan_block(const int* __restrict__ deg, int* __restrict__ incl,
                             int* __restrict__ blocksum, int n) {
    __shared__ int tmp[256];
    int t = threadIdx.x;
    int i = blockIdx.x * 256 + t;
    int v = (i < n) ? deg[i] : 0;
    tmp[t] = v;
    __syncthreads();
    for (int off = 1; off < 256; off <<= 1) {
        int add = (t >= off) ? tmp[t - off] : 0;
        __syncthreads();
        tmp[t] += add;
        __syncthreads();
    }
    if (i < n) incl[i] = tmp[t];
    if (t == 255) blocksum[blockIdx.x] = tmp[t];
}

__global__ void k_scan_top(const int* __restrict__ blocksum, int* __restrict__ blockoff, int nb) {
    __shared__ int tmp[256];
    int t = threadIdx.x;
    int base = 0;
    for (int c = 0; c < nb; c += 256) {
        int i = c + t;
        int v = (i < nb) ? blocksum[i] : 0;
        tmp[t] = v;
        __syncthreads();
        for (int off = 1; off < 256; off <<= 1) {
            int add = (t >= off) ? tmp[t - off] : 0;
            __syncthreads();
            tmp[t] += add;
            __syncthreads();
        }
        if (i < nb) blockoff[i] = base + tmp[t] - v;
        base += tmp[255];
        __syncthreads();
    }
}

__global__ void k_scan_finalize(const int* __restrict__ incl, const int* __restrict__ deg,
                                const int* __restrict__ blockoff, int* __restrict__ rowptr,
                                int n, int n_edges) {
    int i = blockIdx.x * blockDim.x + threadIdx.x;
    if (i < n) rowptr[i] = incl[i] - deg[i] + blockoff[i / 256];
    if (i == 0) rowptr[n] = n_edges;
}

__global__ void k_fill(const int* __restrict__ src, const int* __restrict__ dst,
                       const int* __restrict__ rowptr, int* __restrict__ cursor,
                       int* __restrict__ csr_src, int n_edges) {
    int e = blockIdx.x * blockDim.x + threadIdx.x;
    if (e >= n_edges) return;
    int d = dst[e];
    int pos = atomicAdd(&cursor[d], 1);
    csr_src[rowptr[d] + pos] = src[e];
}

// wave-parallel rank sort: one wave per node (deterministic sorted order).
__global__ void k_sort_wave(const int* __restrict__ rowptr, int* __restrict__ csr_src,
                            int n_nodes) {
    int wid = (blockIdx.x * blockDim.x + threadIdx.x) >> 6;
    int lane = threadIdx.x & 63;
    if (wid >= n_nodes) return;
    int s0 = rowptr[wid], e0 = rowptr[wid + 1];
    int d = e0 - s0;
    if (d <= 1) return;
    if (d <= 64) {
        int v = (lane < d) ? csr_src[s0 + lane] : 0x7FFFFFFF;
        int rank = 0;
        for (int k = 0; k < d; ++k) {
            int vk = __shfl(v, k);
            rank += (vk < v || (vk == v && k < lane)) ? 1 : 0;
        }
        if (lane < d) csr_src[s0 + rank] = v;
    } else if (lane == 0) {
        for (int a = s0 + 1; a < e0; ++a) {
            int key = csr_src[a];
            int b = a - 1;
            while (b >= s0 && csr_src[b] > key) { csr_src[b + 1] = csr_src[b]; --b; }
            csr_src[b + 1] = key;
        }
    }
}

// ================= fused per-node attention (r7 body + persistent grid-stride) ========
// alpha = exp(v)/sum(exp(v)) (== exp(v-m)/sum form exactly; |v| ~<25 here, no overflow).
// Persistent waves: wave w walks nodes w, w+nwaves, ... (2048 resident blocks).
//   p-role: lane -> edge slot lane/H, head lane%H  (EB*H <= 64 slots).
//   f-role: slot r owns feature f = lane + r*64 (per-slot guard, r=0 wave-uniform —
//           this guard shape is the proven no-spill form; do NOT collapse to one isF).
template <int FOUT, int H, int D, int EB>
__global__ void k_node_gather(const int* __restrict__ rowptr, const int* __restrict__ csr_src,
                              const float* __restrict__ el, const float* __restrict__ er,
                              const float* __restrict__ h, const float* __restrict__ bias,
                              float* __restrict__ xout, int n_nodes, int nwaves) {
    constexpr int NF = (FOUT + 63) / 64;
    int wave0 = (blockIdx.x * blockDim.x + threadIdx.x) >> 6;
    int lane = threadIdx.x & 63;

    const int eidx = lane / H;
    const int hh_c = lane % H;

    int f_i[NF], hh_i[NF];
#pragma unroll
    for (int r = 0; r < NF; ++r) {
        int f = lane + r * 64;
        f_i[r] = f;
        hh_i[r] = (f < FOUT) ? (f / D) : 0;
    }

    for (int wid = wave0; wid < n_nodes; wid += nwaves) {
        int start = rowptr[wid], end = rowptr[wid + 1];
        const float er_c = er[wid * H + hh_c];

        float acc[NF];
#pragma unroll
        for (int r = 0; r < NF; ++r) acc[r] = 0.f;
        float den_acc = 0.f;

        if (start < end) {
            int j0 = start;
            int nb = end - j0;
            if (nb > EB) nb = EB;
            int s_c = csr_src[j0 + (eidx < nb ? eidx : 0)];
            float e_c = el[s_c * H + hh_c];

            while (true) {
                int j1 = j0 + nb;
                int nbn = end - j1;
                if (nbn > EB) nbn = EB;
                int s_n = 0;
                float e_n = 0.f;
                if (nbn > 0) {  // prefetch next batch ids + el (hides latency under FMAs)
                    s_n = csr_src[j1 + (eidx < nbn ? eidx : 0)];
                    e_n = el[s_n * H + hh_c];
                }
                // probability (one per p-slot) + butterfly denominator
                float p_c = expf(lrelu(e_c + er_c));
                float pd = (eidx < nb) ? p_c : 0.f;
#pragma unroll
                for (int st = H; st < 64; st <<= 1) pd += __shfl_xor(pd, st);
                den_acc += pd;

                // burst-load edge rows into flat register buffer (static indexing)
                float hv[EB * NF];
#pragma unroll
                for (int e = 0; e < EB; ++e) {
                    if (e < nb) {  // nb wave-uniform
                        int s = __shfl(s_c, e * H);
                        const float* __restrict__ hrow = h + (long long)s * FOUT;
#pragma unroll
                        for (int r = 0; r < NF; ++r)
                            if (f_i[r] < FOUT) hv[e * NF + r] = hrow[f_i[r]];
                    }
                }
                // consume
#pragma unroll
                for (int e = 0; e < EB; ++e) {
                    if (e < nb) {
#pragma unroll
                        for (int r = 0; r < NF; ++r) {
                            float p = __shfl(p_c, e * H + hh_i[r]);
                            if (f_i[r] < FOUT) acc[r] += p * hv[e * NF + r];
                        }
                    }
                }
                if (nbn <= 0) break;
                j0 = j1;
                nb = nbn;
                s_c = s_n;
                e_c = e_n;
            }
        }

        // epilogue: den shfls hoisted outside the divergent f-guard
        float den_r[NF];
#pragma unroll
        for (int r = 0; r < NF; ++r) den_r[r] = __shfl(den_acc, hh_i[r]);
#pragma unroll
        for (int r = 0; r < NF; ++r) {
            if (f_i[r] < FOUT) {
                float val;
                if (end > start) val = acc[r] / den_r[r] + bias[f_i[r]];
                else val = bias[f_i[r]];
                xout[(long long)wid * FOUT + f_i[r]] = val > 0.f ? val : 0.f;
            }
        }
    }
}

// ---- final FC: out = x @ W.T + b (transposed LDS staging)
template <int FIN, int FOUT>
__global__ void k_fc(const float* __restrict__ x, const float* __restrict__ W,
                     const float* __restrict__ b, float* __restrict__ out, int n_nodes) {
    __shared__ float Ws[FIN * FOUT];
    for (int i = threadIdx.x; i < FIN * FOUT; i += blockDim.x) {
        int f = i / FIN, k = i % FIN;
        Ws[k * FOUT + f] = W[i];
    }
    __syncthreads();
    int idx = blockIdx.x * blockDim.x + threadIdx.x;
    if (idx >= n_nodes * FOUT) return;
    int n = idx / FOUT, f = idx % FOUT;
    const float* __restrict__ xr = x + (long long)n * FIN;
    float acc = b[f];
#pragma unroll
    for (int k = 0; k < FIN; ++k) acc += xr[k] * Ws[k * FOUT + f];
    out[idx] = acc;
}

template <int FIN, int FOUT, int H, int D, int EB>
static void gat_layer(const float* x, const float* wext, const float* bias, const int* rowptr,
                      const int* csr_src, int n_nodes, float* bufH, float* el, float* er,
                      float* xnext, hipStream_t stream) {
    constexpr int FOUTE = FOUT + 2 * H;
    k_linear<FIN, FOUT, H><<<cdiv((long long)n_nodes * FOUTE, 256), 256, 0, stream>>>(
        x, wext, bufH, el, er, n_nodes);
    // persistent: 2048 blocks (8/CU) x 4 waves/block = 8192 resident waves
    const int gblocks = 2048;
    const int nwaves = gblocks * (256 / 64);
    k_node_gather<FOUT, H, D, EB><<<gblocks, 256, 0, stream>>>(rowptr, csr_src, el, er, bufH,
                                                               bias, xnext, n_nodes, nwaves);
}

extern "C" void kernel_launch(void* const* d_in, const int* in_sizes, int n_in,
                              void* d_out, int out_size, void* d_ws, size_t ws_size,
                              hipStream_t stream) {
    const float* features = (const float*)d_in[0];
    const int* src = (const int*)d_in[1];
    const int* dst = (const int*)d_in[2];
    const float* W1 = (const float*)d_in[3];
    const float* al1 = (const float*)d_in[4];
    const float* ar1 = (const float*)d_in[5];
    const float* b1 = (const float*)d_in[6];
    const float* W2 = (const float*)d_in[7];
    const float* al2 = (const float*)d_in[8];
    const float* ar2 = (const float*)d_in[9];
    const float* b2 = (const float*)d_in[10];
    const float* W3 = (const float*)d_in[11];
    const float* al3 = (const float*)d_in[12];
    const float* ar3 = (const float*)d_in[13];
    const float* b3 = (const float*)d_in[14];
    const float* fc_w = (const float*)d_in[15];
    const float* fc_b = (const float*)d_in[16];

    const int n_nodes = in_sizes[0] / 25;  // 50000
    const int n_edges = in_sizes[1];       // 1000000
    const int nblocks_nodes = cdiv(n_nodes, 256);

    char* ws = (char*)d_ws;
    size_t off = 0;
    auto alloc = [&](size_t bytes) {
        char* p = ws + off;
        off += (bytes + 255) & ~(size_t)255;
        return p;
    };
    float* bufA = (float*)alloc((size_t)n_nodes * 100 * sizeof(float));
    float* bufH = (float*)alloc((size_t)n_nodes * 100 * sizeof(float));
    float* el = (float*)alloc((size_t)n_nodes * 4 * sizeof(float));
    float* er = (float*)alloc((size_t)n_nodes * 4 * sizeof(float));
    int* degcur = (int*)alloc((size_t)2 * n_nodes * sizeof(int));  // deg | cursor
    int* deg = degcur;
    int* cursor = degcur + n_nodes;
    int* incl = (int*)alloc((size_t)n_nodes * sizeof(int));
    int* blocksum = (int*)alloc((size_t)nblocks_nodes * sizeof(int));
    int* blockoff = (int*)alloc((size_t)nblocks_nodes * sizeof(int));
    int* rowptr = (int*)alloc((size_t)(n_nodes + 1) * sizeof(int));
    int* csr_src = (int*)alloc((size_t)n_edges * sizeof(int));
    float* wx1 = (float*)alloc((size_t)48 * 25 * sizeof(float));
    float* wx2 = (float*)alloc((size_t)108 * 40 * sizeof(float));
    float* wx3 = (float*)alloc((size_t)52 * 100 * sizeof(float));
    (void)ws_size;

    // extended weights (all layers, one launch)
    k_build_wext<<<3, 256, 0, stream>>>(W1, al1, ar1, W2, al2, ar2, W3, al3, ar3, wx1, wx2, wx3);

    // ---- build CSR by dst (shared across all 3 layers)
    hipMemsetAsync(degcur, 0, (size_t)2 * n_nodes * sizeof(int), stream);
    k_deg<<<cdiv(n_edges, 256), 256, 0, stream>>>(dst, deg, n_edges);
    k_scan_block<<<nblocks_nodes, 256, 0, stream>>>(deg, incl, blocksum, n_nodes);
    k_scan_top<<<1, 256, 0, stream>>>(blocksum, blockoff, nblocks_nodes);
    k_scan_finalize<<<cdiv(n_nodes + 1, 256), 256, 0, stream>>>(incl, deg, blockoff, rowptr,
                                                                n_nodes, n_edges);
    k_fill<<<cdiv(n_edges, 256), 256, 0, stream>>>(src, dst, rowptr, cursor, csr_src, n_edges);
    k_sort_wave<<<cdiv((long long)n_nodes * 64, 256), 256, 0, stream>>>(rowptr, csr_src,
                                                                        n_nodes);

    // ---- 3 GAT layers
    gat_layer<25, 40, 4, 10, 16>(features, wx1, b1, rowptr, csr_src, n_nodes, bufH, el, er,
                                 bufA, stream);
    gat_layer<40, 100, 4, 25, 16>(bufA, wx2, b2, rowptr, csr_src, n_nodes, bufH, el, er,
                                  bufA, stream);
    gat_layer<100, 50, 1, 50, 32>(bufA, wx3, b3, rowptr, csr_src, n_nodes, bufH, el, er,
                                  bufA, stream);

    // ---- final FC: 50 -> 93
    k_fc<50, 93><<<cdiv((long long)n_nodes * 93, 256), 256, 0, stream>>>(
        bufA, fc_w, fc_b, (float*)d_out, n_nodes);
}